// Round 13
// baseline (280.133 us; speedup 1.0000x reference)
//
#include <hip/hip_runtime.h>
#include <hip/hip_bf16.h>
#include <cstdint>
#include <cstddef>

#define N_NODES 50000
#define N_PAD   50176    // padded rows for guard-free GEMM tiles
#define N_EDGES 800000
#define D_FEAT  128
#define HALF    64
#define HIDDEN  256
#define LABELS  40

#define NBUCK 196        // ceil(50000/256) buckets of 256 nodes (node>>8)
#define BCAP  5632       // staging cap per bucket; E[cnt]=4096, sigma~64 (24 sigma)
#define EDGES_PER_BLK 4096

#define HID_STRIDE 264   // LDS hidden-tile row stride (bf16): rows 4 banks apart

// Column-panel layout: feature matrices [N_PAD,128] are stored as 8 panels of
// 16 columns. Element (r, c) lives at (c>>4)*PANE + r*16 + (c&15).
// A panel is N_PAD*32B = 1.6 MB < 4 MiB per-XCD L2 -> agg gathers with
// panel = blockIdx%8 keep each XCD's gather working set L2-resident.
#define PANE ((size_t)N_PAD * 16)

typedef __attribute__((ext_vector_type(8))) short bf16x8;
typedef __attribute__((ext_vector_type(4))) float f32x4;

// Packed-weight layout offsets (in bf16 elements).
#define PK_SELF(L) ((size_t)(L) * 8192)
#define PK_NBR(L)  (24576 + (size_t)(L) * 8192)
#define PK_W1      49152
#define PK_W2      81920
#define PK_TOTAL   94208

__device__ inline uint16_t f2bf_bits(float f) {
    __hip_bfloat16 b = __float2bfloat16(f);
    uint16_t u; __builtin_memcpy(&u, &b, 2); return u;
}

// ---------------------------------------------------------------------------
// CSR build phase 1: bucket scatter. 196 blocks x 4096 edges.
// ---------------------------------------------------------------------------
__global__ __launch_bounds__(1024) void bucket_scatter_kernel(
        const int* __restrict__ row, const int* __restrict__ col,
        int* __restrict__ bucket_cursor, uint32_t* __restrict__ staged) {
    __shared__ int hist[NBUCK];
    __shared__ int hbase[NBUCK];
    int tid  = threadIdx.x;
    int e0   = blockIdx.x * EDGES_PER_BLK;
    int eend = e0 + EDGES_PER_BLK; if (eend > N_EDGES) eend = N_EDGES;

    for (int i = tid; i < NBUCK; i += 1024) hist[i] = 0;
    __syncthreads();

    int rr[4], cc[4]; int ne = 0;
    for (int e = e0 + tid; e < eend; e += 1024) {
        rr[ne] = row[e]; cc[ne] = col[e]; ne++;
    }
    for (int i = 0; i < ne; i++) atomicAdd(&hist[rr[i] >> 8], 1);
    __syncthreads();

    for (int i = tid; i < NBUCK; i += 1024) {
        hbase[i] = atomicAdd(&bucket_cursor[i], hist[i]);
        hist[i]  = 0;
    }
    __syncthreads();

    for (int i = 0; i < ne; i++) {
        int b   = rr[i] >> 8;
        int off = atomicAdd(&hist[b], 1);
        int pos = hbase[b] + off;
        if (pos < BCAP)
            staged[(size_t)b * BCAP + pos] =
                ((uint32_t)(rr[i] & 255) << 16) | (uint32_t)cc[i];
    }
}

// ---------------------------------------------------------------------------
// CSR build phase 2: one block per bucket -> deg/rowstart/inv_deg/csr_col.
// Block-local prefix of the 196 bucket sizes replaces a separate scan kernel.
// ---------------------------------------------------------------------------
__global__ __launch_bounds__(1024) void bucket_fill_kernel(
        const uint32_t* __restrict__ staged, const int* __restrict__ bucket_cursor,
        int* __restrict__ deg, int* __restrict__ rowstart,
        float* __restrict__ inv_deg, int* __restrict__ csr_col) {
    __shared__ int cnt[256];
    __shared__ int excl[256];
    __shared__ int wt[4];
    __shared__ int seg[BCAP];
    __shared__ int base_s;
    int b   = blockIdx.x;
    int tid = threadIdx.x;

    if (tid < 64) {                      // wave 0: gbase = sum cursor[i<b]
        int partial = 0;
        for (int i = tid; i < b; i += 64) partial += bucket_cursor[i];
#pragma unroll
        for (int off = 32; off > 0; off >>= 1)
            partial += __shfl_down(partial, off, 64);
        if (tid == 0) base_s = partial;
    }
    if (tid < 256) cnt[tid] = 0;
    __syncthreads();

    int total = bucket_cursor[b]; if (total > BCAP) total = BCAP;
    int gbase = base_s;
    const uint32_t* st = staged + (size_t)b * BCAP;

    for (int i = tid; i < total; i += 1024) atomicAdd(&cnt[st[i] >> 16], 1);
    __syncthreads();

    int lane = tid & 63, wid = tid >> 6;
    int v = 0, s = 0;
    if (tid < 256) {
        v = cnt[tid]; s = v;
#pragma unroll
        for (int off = 1; off < 64; off <<= 1) {
            int t = __shfl_up(s, off, 64);
            if (lane >= off) s += t;
        }
        if (lane == 63) wt[wid] = s;
    }
    __syncthreads();
    if (tid == 0) { int a = 0; for (int i = 0; i < 4; i++) { int t = wt[i]; wt[i] = a; a += t; } }
    __syncthreads();
    if (tid < 256) {
        int ex = s - v + wt[wid];
        excl[tid] = ex;
        int node = (b << 8) + tid;
        if (node < N_NODES) {
            deg[node]      = v;
            rowstart[node] = gbase + ex;
            inv_deg[node]  = 1.0f / fmaxf((float)v, 1.0f);
        }
    }
    __syncthreads();
    for (int i = tid; i < total; i += 1024) {
        uint32_t u = st[i];
        int p = atomicAdd(&excl[u >> 16], 1);
        seg[p] = (int)(u & 0xffffu);
    }
    __syncthreads();
    for (int i = tid; i < total; i += 1024) csr_col[gbase + i] = seg[i];
}

// ---------------------------------------------------------------------------
// x (fp32, row-major) -> bf16 panel layout.
// t -> (panel, node, half): writes are fully contiguous per panel.
// ---------------------------------------------------------------------------
__global__ __launch_bounds__(256) void xcast_panel_kernel(
        const float* __restrict__ x, __hip_bfloat16* __restrict__ hP) {
    int idx = blockIdx.x * blockDim.x + threadIdx.x;   // < 8 * N_NODES * 2
    if (idx >= 8 * N_NODES * 2) return;
    int p    = idx / (N_NODES * 2);
    int rem  = idx - p * (N_NODES * 2);
    int node = rem >> 1;
    int half = rem & 1;
    const float* src = x + (size_t)node * D_FEAT + p * 16 + half * 8;
    float4 v0 = *(const float4*)src;
    float4 v1 = *(const float4*)(src + 4);
    uint2 o0, o1;
    o0.x = (uint32_t)f2bf_bits(v0.x) | ((uint32_t)f2bf_bits(v0.y) << 16);
    o0.y = (uint32_t)f2bf_bits(v0.z) | ((uint32_t)f2bf_bits(v0.w) << 16);
    o1.x = (uint32_t)f2bf_bits(v1.x) | ((uint32_t)f2bf_bits(v1.y) << 16);
    o1.y = (uint32_t)f2bf_bits(v1.z) | ((uint32_t)f2bf_bits(v1.w) << 16);
    uint32_t* dst = (uint32_t*)(hP + (size_t)p * PANE + (size_t)node * 16 + half * 8);
    dst[0] = o0.x; dst[1] = o0.y; dst[2] = o1.x; dst[3] = o1.y;
}

// ---------------------------------------------------------------------------
// Pack all weights to bf16 in MFMA B-fragment order.
//   pack[((ns*ksteps + ks)*64 + l)*8 + j] = W[ks*32 + (l>>4)*8 + j][ns*16 + (l&15)]
// ---------------------------------------------------------------------------
__global__ __launch_bounds__(256) void pack_all_kernel(
        const float* __restrict__ selfk, const float* __restrict__ nbrk,
        const float* __restrict__ w1, const float* __restrict__ w2,
        __hip_bfloat16* __restrict__ wpack) {
    int m = blockIdx.y;
    const float* W; int K, Ncols, Npad; size_t dstoff;
    if (m < 3)      { W = selfk + (size_t)m*D_FEAT*HALF;      K=128; Ncols=64;  Npad=64;  dstoff = PK_SELF(m); }
    else if (m < 6) { W = nbrk  + (size_t)(m-3)*D_FEAT*HALF;  K=128; Ncols=64;  Npad=64;  dstoff = PK_NBR(m-3); }
    else if (m == 6){ W = w1;                                 K=128; Ncols=256; Npad=256; dstoff = PK_W1; }
    else            { W = w2;                                 K=256; Ncols=40;  Npad=48;  dstoff = PK_W2; }
    int ksteps = K / 32;
    int total  = ksteps * (Npad / 16) * 64;
    int t = blockIdx.x * blockDim.x + threadIdx.x;
    if (t >= total) return;
    int lane = t & 63;
    int rest = t >> 6;
    int ks   = rest % ksteps;
    int ns   = rest / ksteps;
    int colb = ns * 16 + (lane & 15);
    int kb   = ks * 32 + (lane >> 4) * 8;
    __hip_bfloat16* dst = wpack + dstoff + (size_t)t * 8;
#pragma unroll
    for (int j = 0; j < 8; j++) {
        float v = (colb < Ncols) ? W[(size_t)(kb + j) * Ncols + colb] : 0.f;
        dst[j] = __float2bfloat16(v);
    }
}

// ---------------------------------------------------------------------------
// Mean-neighbor aggregation over PANELS: panel = blockIdx%8 (XCD-affine).
// 4 lanes/node (8B each over the 32B panel row), 16 nodes/wave, 8-deep
// row-gather pipeline + 8-ahead index prefetch. Ascending-j accumulation
// per element -> bit-identical to the row-major version.
// ---------------------------------------------------------------------------
__global__ __launch_bounds__(256) void agg_panel_kernel(
        const __hip_bfloat16* __restrict__ hP, const int* __restrict__ csr_col,
        const int* __restrict__ rowstart, const int* __restrict__ deg,
        const float* __restrict__ inv_deg, __hip_bfloat16* __restrict__ nbrP) {
    int panel = blockIdx.x & 7;
    int chunk = blockIdx.x >> 3;           // 0..783
    int wave  = threadIdx.x >> 6;
    int lane  = threadIdx.x & 63;
    int sub   = lane >> 2;                 // node slot (0..15)
    int q     = lane & 3;                  // uint2 quarter of 32B panel row
    int node  = (chunk * 4 + wave) * 16 + sub;    // < N_PAD
    int ne    = min(node, N_NODES - 1);    // clamp metadata for padding rows
    int start = rowstart[ne];
    int d     = deg[ne];
    const uint32_t* hw = (const uint32_t*)(hP + (size_t)panel * PANE); // row = 8 dwords
    float acc[4] = {};

#define ACC4(U)                                        \
    acc[0] += __uint_as_float((U).x << 16);            \
    acc[1] += __uint_as_float((U).x & 0xffff0000u);    \
    acc[2] += __uint_as_float((U).y << 16);            \
    acc[3] += __uint_as_float((U).y & 0xffff0000u);

    if (d > 0) {
        int last = start + d - 1;
        int s[8];
#pragma unroll
        for (int k = 0; k < 8; k++) s[k] = csr_col[min(start + k, last)];
        int j = 0;
        for (; j + 8 <= d; j += 8) {
            int p[8];
#pragma unroll
            for (int k = 0; k < 8; k++) p[k] = csr_col[min(start + j + 8 + k, last)];
            uint2 u0 = *(const uint2*)(hw + (size_t)s[0] * 8 + q * 2);
            uint2 u1 = *(const uint2*)(hw + (size_t)s[1] * 8 + q * 2);
            uint2 u2 = *(const uint2*)(hw + (size_t)s[2] * 8 + q * 2);
            uint2 u3 = *(const uint2*)(hw + (size_t)s[3] * 8 + q * 2);
            uint2 u4 = *(const uint2*)(hw + (size_t)s[4] * 8 + q * 2);
            uint2 u5 = *(const uint2*)(hw + (size_t)s[5] * 8 + q * 2);
            uint2 u6 = *(const uint2*)(hw + (size_t)s[6] * 8 + q * 2);
            uint2 u7 = *(const uint2*)(hw + (size_t)s[7] * 8 + q * 2);
            ACC4(u0); ACC4(u1); ACC4(u2); ACC4(u3);
            ACC4(u4); ACC4(u5); ACC4(u6); ACC4(u7);
#pragma unroll
            for (int k = 0; k < 8; k++) s[k] = p[k];
        }
        int r = d - j;                     // tail in [0,7]
#pragma unroll
        for (int k = 0; k < 8; k++) {
            if (k < r) {
                uint2 u = *(const uint2*)(hw + (size_t)s[k] * 8 + q * 2);
                ACC4(u);
            }
        }
    }
#undef ACC4

    float inv = inv_deg[ne];
    uint2 p;
    p.x = (uint32_t)f2bf_bits(acc[0] * inv) | ((uint32_t)f2bf_bits(acc[1] * inv) << 16);
    p.y = (uint32_t)f2bf_bits(acc[2] * inv) | ((uint32_t)f2bf_bits(acc[3] * inv) << 16);
    *(uint2*)((uint32_t*)(nbrP + (size_t)panel * PANE) + (size_t)node * 8 + q * 2) = p;
}

// ---------------------------------------------------------------------------
// Layer GEMM (MFMA), panel-layout A and outputs:
//   out[:,0:64] = relu(h@Wself+b[0:64]); out[:,64:128] = relu(nbr@Wnbr+b[64:]).
// A-frag (row r, ks, lgrp): panel = ks*2 + (lgrp>>1), elem r*16 + (lgrp&1)*8.
// Stores: colS=ns*16+lrow -> panel ns; colN -> panel 4+ns; elem r*16+lrow.
// ---------------------------------------------------------------------------
__global__ __launch_bounds__(256, 2) void layer_fused_kernel(
        const __hip_bfloat16* __restrict__ h, const __hip_bfloat16* __restrict__ nbr,
        const __hip_bfloat16* __restrict__ wpack_self,
        const __hip_bfloat16* __restrict__ wpack_nbr,
        const float* __restrict__ bias, __hip_bfloat16* __restrict__ out) {
    int wave = threadIdx.x >> 6, lane = threadIdx.x & 63;
    int row0 = blockIdx.x * 128 + wave * 32;
    int lrow = lane & 15, lgrp = lane >> 4;
    size_t psel = (size_t)(lgrp >> 1) * PANE;
    size_t rb0  = (size_t)(row0 + lrow) * 16 + (lgrp & 1) * 8;
    size_t rb1  = rb0 + 16 * 16;

    f32x4 accS[2][4] = {};
    f32x4 accN[2][4] = {};
#pragma unroll
    for (int ks = 0; ks < 4; ks++) {
        size_t pk = psel + (size_t)(ks * 2) * PANE;
        bf16x8 ah0 = *(const bf16x8*)(h   + pk + rb0);
        bf16x8 ah1 = *(const bf16x8*)(h   + pk + rb1);
        bf16x8 an0 = *(const bf16x8*)(nbr + pk + rb0);
        bf16x8 an1 = *(const bf16x8*)(nbr + pk + rb1);
#pragma unroll
        for (int ns = 0; ns < 4; ns++) {
            bf16x8 bs = *(const bf16x8*)(wpack_self + ((size_t)(ns * 4 + ks) * 64 + lane) * 8);
            accS[0][ns] = __builtin_amdgcn_mfma_f32_16x16x32_bf16(ah0, bs, accS[0][ns], 0, 0, 0);
            accS[1][ns] = __builtin_amdgcn_mfma_f32_16x16x32_bf16(ah1, bs, accS[1][ns], 0, 0, 0);
            bf16x8 bn = *(const bf16x8*)(wpack_nbr + ((size_t)(ns * 4 + ks) * 64 + lane) * 8);
            accN[0][ns] = __builtin_amdgcn_mfma_f32_16x16x32_bf16(an0, bn, accN[0][ns], 0, 0, 0);
            accN[1][ns] = __builtin_amdgcn_mfma_f32_16x16x32_bf16(an1, bn, accN[1][ns], 0, 0, 0);
        }
    }
#pragma unroll
    for (int t = 0; t < 2; t++) {
#pragma unroll
        for (int ns = 0; ns < 4; ns++) {
            float bvS = bias[ns * 16 + lrow];
            float bvN = bias[HALF + ns * 16 + lrow];
#pragma unroll
            for (int i = 0; i < 4; i++) {
                int r = row0 + t * 16 + lgrp * 4 + i;     // < N_PAD, unguarded
                out[(size_t)ns * PANE + (size_t)r * 16 + lrow] =
                    __float2bfloat16(fmaxf(accS[t][ns][i] + bvS, 0.f));
                out[(size_t)(4 + ns) * PANE + (size_t)r * 16 + lrow] =
                    __float2bfloat16(fmaxf(accN[t][ns][i] + bvN, 0.f));
            }
        }
    }
}

// ---------------------------------------------------------------------------
// Fused MLP: out[N,40] = relu(h@W1+b1) @ W2 + b2. h in panel layout.
// Phase 1 -> LDS hidden tile; Phase 2 from LDS; fp32 row-major out (d_out).
// ---------------------------------------------------------------------------
__global__ __launch_bounds__(256, 2) void mlp_fused_kernel(
        const __hip_bfloat16* __restrict__ h, const __hip_bfloat16* __restrict__ w1p,
        const float* __restrict__ b1, const __hip_bfloat16* __restrict__ w2p,
        const float* __restrict__ b2, float* __restrict__ out) {
    __shared__ __align__(16) uint16_t hid[128 * HID_STRIDE];   // 67584 B
    int wave = threadIdx.x >> 6, lane = threadIdx.x & 63;
    int row0 = blockIdx.x * 128 + wave * 32;
    int lrow = lane & 15, lgrp = lane >> 4;

    // ---- Phase 1: hidden = relu(h @ W1 + b1) -> LDS ----
    {
        size_t psel = (size_t)(lgrp >> 1) * PANE;
        size_t rb0  = (size_t)(row0 + lrow) * 16 + (lgrp & 1) * 8;
        size_t rb1  = rb0 + 16 * 16;
        f32x4 acc[2][16] = {};
#pragma unroll 1
        for (int ks = 0; ks < 4; ks++) {
            size_t pk = psel + (size_t)(ks * 2) * PANE;
            bf16x8 a0 = *(const bf16x8*)(h + pk + rb0);
            bf16x8 a1 = *(const bf16x8*)(h + pk + rb1);
#pragma unroll
            for (int ns = 0; ns < 16; ns++) {
                bf16x8 bfr = *(const bf16x8*)(w1p + ((size_t)(ns * 4 + ks) * 64 + lane) * 8);
                acc[0][ns] = __builtin_amdgcn_mfma_f32_16x16x32_bf16(a0, bfr, acc[0][ns], 0, 0, 0);
                acc[1][ns] = __builtin_amdgcn_mfma_f32_16x16x32_bf16(a1, bfr, acc[1][ns], 0, 0, 0);
            }
        }
        int lbase = wave * 32;
#pragma unroll
        for (int t = 0; t < 2; t++) {
#pragma unroll
            for (int ns = 0; ns < 16; ns++) {
                int col = ns * 16 + lrow;
                float bv = b1[col];
#pragma unroll
                for (int i = 0; i < 4; i++) {
                    int lr = lbase + t * 16 + lgrp * 4 + i;
                    hid[lr * HID_STRIDE + col] =
                        f2bf_bits(fmaxf(acc[t][ns][i] + bv, 0.f));
                }
            }
        }
    }
    __syncthreads();

    // ---- Phase 2: out = hidden @ W2 + b2 ----
    const uint16_t* br0 = &hid[(wave * 32 + lrow) * HID_STRIDE + lgrp * 8];
    const uint16_t* br1 = br0 + 16 * HID_STRIDE;
    f32x4 acc2[2][3] = {};
#pragma unroll
    for (int ks = 0; ks < 8; ks++) {
        bf16x8 a0 = *(const bf16x8*)(br0 + ks * 32);
        bf16x8 a1 = *(const bf16x8*)(br1 + ks * 32);
#pragma unroll
        for (int ns = 0; ns < 3; ns++) {
            bf16x8 bfr = *(const bf16x8*)(w2p + ((size_t)(ns * 8 + ks) * 64 + lane) * 8);
            acc2[0][ns] = __builtin_amdgcn_mfma_f32_16x16x32_bf16(a0, bfr, acc2[0][ns], 0, 0, 0);
            acc2[1][ns] = __builtin_amdgcn_mfma_f32_16x16x32_bf16(a1, bfr, acc2[1][ns], 0, 0, 0);
        }
    }
#pragma unroll
    for (int t = 0; t < 2; t++) {
#pragma unroll
        for (int ns = 0; ns < 3; ns++) {
            int col = ns * 16 + lrow;
            if (col < LABELS) {
                float bv = b2[col];
#pragma unroll
                for (int i = 0; i < 4; i++) {
                    int r = row0 + t * 16 + lgrp * 4 + i;
                    if (r < N_NODES)                       // d_out: exact size
                        out[(size_t)r * LABELS + col] = acc2[t][ns][i] + bv;
                }
            }
        }
    }
}

// ---------------------------------------------------------------------------
extern "C" void kernel_launch(void* const* d_in, const int* in_sizes, int n_in,
                              void* d_out, int out_size, void* d_ws, size_t ws_size,
                              hipStream_t stream) {
    const float* x      = (const float*)d_in[0];
    const int*   ei     = (const int*)d_in[1];
    const float* selfk  = (const float*)d_in[2];
    const float* nbrk   = (const float*)d_in[3];
    const float* biases = (const float*)d_in[4];
    const float* w1     = (const float*)d_in[5];
    const float* b1     = (const float*)d_in[6];
    const float* w2     = (const float*)d_in[7];
    const float* b2     = (const float*)d_in[8];
    float* out = (float*)d_out;

    const int* row = ei;             // targets
    const int* col = ei + N_EDGES;   // sources

    char* ws = (char*)d_ws;
    size_t off = 0;
    auto alloc = [&](size_t bytes) -> char* {
        char* p = ws + off;
        off = (off + bytes + 255) & ~(size_t)255;
        return p;
    };
    int*   deg       = (int*)  alloc((size_t)N_NODES * 4);
    int*   rowstart  = (int*)  alloc((size_t)N_NODES * 4);
    float* inv_deg   = (float*)alloc((size_t)N_NODES * 4);
    int*   bucket_cursor = (int*)alloc(256 * 4);
    int*   csr_col   = (int*)  alloc((size_t)N_EDGES * 4);
    uint32_t* staged = (uint32_t*)alloc((size_t)NBUCK * BCAP * 4);
    __hip_bfloat16* wpack  = (__hip_bfloat16*)alloc(PK_TOTAL * 2);
    __hip_bfloat16* xb     = (__hip_bfloat16*)alloc((size_t)N_PAD * D_FEAT * 2);
    __hip_bfloat16* hA     = (__hip_bfloat16*)alloc((size_t)N_PAD * D_FEAT * 2);
    __hip_bfloat16* hB     = (__hip_bfloat16*)alloc((size_t)N_PAD * D_FEAT * 2);
    __hip_bfloat16* nbrbuf = (__hip_bfloat16*)alloc((size_t)N_PAD * D_FEAT * 2);

    hipMemsetAsync(bucket_cursor, 0, 256 * 4, stream);

    const int scat_blocks = (N_EDGES + EDGES_PER_BLK - 1) / EDGES_PER_BLK;  // 196
    bucket_scatter_kernel<<<scat_blocks, 1024, 0, stream>>>(row, col, bucket_cursor, staged);
    bucket_fill_kernel<<<NBUCK, 1024, 0, stream>>>(staged, bucket_cursor,
                                                   deg, rowstart, inv_deg, csr_col);

    xcast_panel_kernel<<<(8 * N_NODES * 2 + 255) / 256, 256, 0, stream>>>(x, xb);
    dim3 pgrid(16, 8);
    pack_all_kernel<<<pgrid, 256, 0, stream>>>(selfk, nbrk, w1, w2, wpack);

    const int agg_blocks   = (N_PAD / 64) * 8;             // 784 chunks x 8 panels = 6272
    const int layer_blocks = N_PAD / 128;
    const int mlp_blocks   = N_PAD / 128;

    const __hip_bfloat16* hcur = xb;
    __hip_bfloat16* bufs[3] = {hA, hB, hA};
    for (int L = 0; L < 3; L++) {
        agg_panel_kernel<<<agg_blocks, 256, 0, stream>>>(hcur, csr_col, rowstart, deg,
                                                         inv_deg, nbrbuf);
        layer_fused_kernel<<<layer_blocks, 256, 0, stream>>>(
            hcur, nbrbuf, wpack + PK_SELF(L), wpack + PK_NBR(L),
            biases + (size_t)L * (2 * HALF), bufs[L]);
        hcur = bufs[L];
    }

    mlp_fused_kernel<<<mlp_blocks, 256, 0, stream>>>(hcur, wpack + PK_W1, b1,
                                                     wpack + PK_W2, b2, out);
}

// Round 14
// 246.504 us; speedup vs baseline: 1.1364x; 1.1364x over previous
//
#include <hip/hip_runtime.h>
#include <hip/hip_bf16.h>
#include <cstdint>
#include <cstddef>

#define N_NODES 50000
#define N_PAD   50176    // padded rows for guard-free GEMM tiles
#define N_EDGES 800000
#define D_FEAT  128
#define HALF    64
#define HIDDEN  256
#define LABELS  40

#define NBUCK 196        // ceil(50000/256) buckets of 256 nodes (node>>8)
#define BCAP  5632       // staging cap per bucket; E[cnt]=4096, sigma~64 (24 sigma)
#define EDGES_PER_BLK 4096

#define HID_STRIDE 264   // LDS hidden-tile row stride (bf16): rows 4 banks apart

typedef __attribute__((ext_vector_type(8))) short bf16x8;
typedef __attribute__((ext_vector_type(4))) float f32x4;

// Packed-weight layout offsets (in bf16 elements).
#define PK_SELF(L) ((size_t)(L) * 8192)
#define PK_NBR(L)  (24576 + (size_t)(L) * 8192)
#define PK_W1      49152
#define PK_W2      81920
#define PK_TOTAL   94208

__device__ inline uint16_t f2bf_bits(float f) {
    __hip_bfloat16 b = __float2bfloat16(f);
    uint16_t u; __builtin_memcpy(&u, &b, 2); return u;
}

// ---------------------------------------------------------------------------
// CSR build phase 1: bucket scatter. 196 blocks x 4096 edges.
// ---------------------------------------------------------------------------
__global__ __launch_bounds__(1024) void bucket_scatter_kernel(
        const int* __restrict__ row, const int* __restrict__ col,
        int* __restrict__ bucket_cursor, uint32_t* __restrict__ staged) {
    __shared__ int hist[NBUCK];
    __shared__ int hbase[NBUCK];
    int tid  = threadIdx.x;
    int e0   = blockIdx.x * EDGES_PER_BLK;
    int eend = e0 + EDGES_PER_BLK; if (eend > N_EDGES) eend = N_EDGES;

    for (int i = tid; i < NBUCK; i += 1024) hist[i] = 0;
    __syncthreads();

    int rr[4], cc[4]; int ne = 0;
    for (int e = e0 + tid; e < eend; e += 1024) {
        rr[ne] = row[e]; cc[ne] = col[e]; ne++;
    }
    for (int i = 0; i < ne; i++) atomicAdd(&hist[rr[i] >> 8], 1);
    __syncthreads();

    for (int i = tid; i < NBUCK; i += 1024) {
        hbase[i] = atomicAdd(&bucket_cursor[i], hist[i]);
        hist[i]  = 0;
    }
    __syncthreads();

    for (int i = 0; i < ne; i++) {
        int b   = rr[i] >> 8;
        int off = atomicAdd(&hist[b], 1);
        int pos = hbase[b] + off;
        if (pos < BCAP)
            staged[(size_t)b * BCAP + pos] =
                ((uint32_t)(rr[i] & 255) << 16) | (uint32_t)cc[i];
    }
}

// ---------------------------------------------------------------------------
// CSR build phase 2: one block per bucket -> deg/rowstart/inv_deg/csr_col.
// Block-local prefix of the 196 bucket sizes replaces the old scan kernel.
// ---------------------------------------------------------------------------
__global__ __launch_bounds__(1024) void bucket_fill_kernel(
        const uint32_t* __restrict__ staged, const int* __restrict__ bucket_cursor,
        int* __restrict__ deg, int* __restrict__ rowstart,
        float* __restrict__ inv_deg, int* __restrict__ csr_col) {
    __shared__ int cnt[256];
    __shared__ int excl[256];
    __shared__ int wt[4];
    __shared__ int seg[BCAP];
    __shared__ int base_s;
    int b   = blockIdx.x;
    int tid = threadIdx.x;

    if (tid < 64) {                      // wave 0: gbase = sum cursor[i<b]
        int partial = 0;
        for (int i = tid; i < b; i += 64) partial += bucket_cursor[i];
#pragma unroll
        for (int off = 32; off > 0; off >>= 1)
            partial += __shfl_down(partial, off, 64);
        if (tid == 0) base_s = partial;
    }
    if (tid < 256) cnt[tid] = 0;
    __syncthreads();

    int total = bucket_cursor[b]; if (total > BCAP) total = BCAP;
    int gbase = base_s;
    const uint32_t* st = staged + (size_t)b * BCAP;

    for (int i = tid; i < total; i += 1024) atomicAdd(&cnt[st[i] >> 16], 1);
    __syncthreads();

    int lane = tid & 63, wid = tid >> 6;
    int v = 0, s = 0;
    if (tid < 256) {
        v = cnt[tid]; s = v;
#pragma unroll
        for (int off = 1; off < 64; off <<= 1) {
            int t = __shfl_up(s, off, 64);
            if (lane >= off) s += t;
        }
        if (lane == 63) wt[wid] = s;
    }
    __syncthreads();
    if (tid == 0) { int a = 0; for (int i = 0; i < 4; i++) { int t = wt[i]; wt[i] = a; a += t; } }
    __syncthreads();
    if (tid < 256) {
        int ex = s - v + wt[wid];
        excl[tid] = ex;
        int node = (b << 8) + tid;
        if (node < N_NODES) {
            deg[node]      = v;
            rowstart[node] = gbase + ex;
            inv_deg[node]  = 1.0f / fmaxf((float)v, 1.0f);
        }
    }
    __syncthreads();
    for (int i = tid; i < total; i += 1024) {
        uint32_t u = st[i];
        int p = atomicAdd(&excl[u >> 16], 1);
        seg[p] = (int)(u & 0xffffu);
    }
    __syncthreads();
    for (int i = tid; i < total; i += 1024) csr_col[gbase + i] = seg[i];
}

// ---------------------------------------------------------------------------
// x (fp32) -> bf16
// ---------------------------------------------------------------------------
__global__ __launch_bounds__(256) void xcast_kernel(
        const float* __restrict__ x, __hip_bfloat16* __restrict__ xb) {
    size_t i = (size_t)(blockIdx.x * blockDim.x + threadIdx.x) * 4;
    if (i >= (size_t)N_NODES * D_FEAT) return;
    float4 v = *(const float4*)(x + i);
    uint2 p;
    p.x = (uint32_t)f2bf_bits(v.x) | ((uint32_t)f2bf_bits(v.y) << 16);
    p.y = (uint32_t)f2bf_bits(v.z) | ((uint32_t)f2bf_bits(v.w) << 16);
    *(uint2*)((uint16_t*)xb + i) = p;
}

// ---------------------------------------------------------------------------
// Pack all weights to bf16 in MFMA B-fragment order.
//   pack[((ns*ksteps + ks)*64 + l)*8 + j] = W[ks*32 + (l>>4)*8 + j][ns*16 + (l&15)]
// ---------------------------------------------------------------------------
__global__ __launch_bounds__(256) void pack_all_kernel(
        const float* __restrict__ selfk, const float* __restrict__ nbrk,
        const float* __restrict__ w1, const float* __restrict__ w2,
        __hip_bfloat16* __restrict__ wpack) {
    int m = blockIdx.y;
    const float* W; int K, Ncols, Npad; size_t dstoff;
    if (m < 3)      { W = selfk + (size_t)m*D_FEAT*HALF;      K=128; Ncols=64;  Npad=64;  dstoff = PK_SELF(m); }
    else if (m < 6) { W = nbrk  + (size_t)(m-3)*D_FEAT*HALF;  K=128; Ncols=64;  Npad=64;  dstoff = PK_NBR(m-3); }
    else if (m == 6){ W = w1;                                 K=128; Ncols=256; Npad=256; dstoff = PK_W1; }
    else            { W = w2;                                 K=256; Ncols=40;  Npad=48;  dstoff = PK_W2; }
    int ksteps = K / 32;
    int total  = ksteps * (Npad / 16) * 64;
    int t = blockIdx.x * blockDim.x + threadIdx.x;
    if (t >= total) return;
    int lane = t & 63;
    int rest = t >> 6;
    int ks   = rest % ksteps;
    int ns   = rest / ksteps;
    int colb = ns * 16 + (lane & 15);
    int kb   = ks * 32 + (lane >> 4) * 8;
    __hip_bfloat16* dst = wpack + dstoff + (size_t)t * 8;
#pragma unroll
    for (int j = 0; j < 8; j++) {
        float v = (colb < Ncols) ? W[(size_t)(kb + j) * Ncols + colb] : 0.f;
        dst[j] = __float2bfloat16(v);
    }
}

// ---------------------------------------------------------------------------
// Mean-neighbor aggregation: 4 nodes/wave, 16 lanes/node, dwordx4 loads,
// EIGHT independent row-gathers in flight per lane + 8-ahead index prefetch.
// Accumulation stays in ascending-j order -> bit-identical to r9/r11.
// ---------------------------------------------------------------------------
__global__ __launch_bounds__(256) void agg4_kernel(
        const __hip_bfloat16* __restrict__ h, const int* __restrict__ csr_col,
        const int* __restrict__ rowstart, const int* __restrict__ deg,
        const float* __restrict__ inv_deg, __hip_bfloat16* __restrict__ nbr) {
    int gid  = blockIdx.x * blockDim.x + threadIdx.x;
    int wnum = gid >> 6;
    int lane = threadIdx.x & 63;
    int sub  = lane >> 4;                // node slot within wave (0..3)
    int sl   = lane & 15;                // covers dwords [4*sl, 4*sl+3] of the row
    int node = wnum * 4 + sub;           // grid exact: 12500 waves * 4 = 50000
    int start = rowstart[node];
    int d     = deg[node];
    const uint32_t* hw = (const uint32_t*)h;   // row = 64 dwords
    float acc[8] = {};

#define ACC8(U)                                        \
    acc[0] += __uint_as_float((U).x << 16);            \
    acc[1] += __uint_as_float((U).x & 0xffff0000u);    \
    acc[2] += __uint_as_float((U).y << 16);            \
    acc[3] += __uint_as_float((U).y & 0xffff0000u);    \
    acc[4] += __uint_as_float((U).z << 16);            \
    acc[5] += __uint_as_float((U).z & 0xffff0000u);    \
    acc[6] += __uint_as_float((U).w << 16);            \
    acc[7] += __uint_as_float((U).w & 0xffff0000u);

    if (d > 0) {
        int last = start + d - 1;
        int s[8];
#pragma unroll
        for (int k = 0; k < 8; k++) s[k] = csr_col[min(start + k, last)];
        int j = 0;
        for (; j + 8 <= d; j += 8) {
            int p[8];
#pragma unroll
            for (int k = 0; k < 8; k++) p[k] = csr_col[min(start + j + 8 + k, last)];
            uint4 u0 = *(const uint4*)(hw + (size_t)s[0] * 64 + sl * 4);
            uint4 u1 = *(const uint4*)(hw + (size_t)s[1] * 64 + sl * 4);
            uint4 u2 = *(const uint4*)(hw + (size_t)s[2] * 64 + sl * 4);
            uint4 u3 = *(const uint4*)(hw + (size_t)s[3] * 64 + sl * 4);
            uint4 u4 = *(const uint4*)(hw + (size_t)s[4] * 64 + sl * 4);
            uint4 u5 = *(const uint4*)(hw + (size_t)s[5] * 64 + sl * 4);
            uint4 u6 = *(const uint4*)(hw + (size_t)s[6] * 64 + sl * 4);
            uint4 u7 = *(const uint4*)(hw + (size_t)s[7] * 64 + sl * 4);
            ACC8(u0); ACC8(u1); ACC8(u2); ACC8(u3);
            ACC8(u4); ACC8(u5); ACC8(u6); ACC8(u7);
#pragma unroll
            for (int k = 0; k < 8; k++) s[k] = p[k];
        }
        // tail: r = d - j in [0,7]; s[0..r-1] hold the remaining indices.
        int r = d - j;
#pragma unroll
        for (int k = 0; k < 8; k++) {
            if (k < r) {
                uint4 u = *(const uint4*)(hw + (size_t)s[k] * 64 + sl * 4);
                ACC8(u);
            }
        }
    }
#undef ACC8

    float inv = inv_deg[node];
    uint4 p;
    p.x = (uint32_t)f2bf_bits(acc[0] * inv) | ((uint32_t)f2bf_bits(acc[1] * inv) << 16);
    p.y = (uint32_t)f2bf_bits(acc[2] * inv) | ((uint32_t)f2bf_bits(acc[3] * inv) << 16);
    p.z = (uint32_t)f2bf_bits(acc[4] * inv) | ((uint32_t)f2bf_bits(acc[5] * inv) << 16);
    p.w = (uint32_t)f2bf_bits(acc[6] * inv) | ((uint32_t)f2bf_bits(acc[7] * inv) << 16);
    *(uint4*)((uint32_t*)nbr + (size_t)node * 64 + sl * 4) = p;
}

// ---------------------------------------------------------------------------
// Layer GEMM (MFMA), fused halves: out[N,128] = relu([h@Wself | nbr@Wnbr]+b).
// One wave does 32 rows x both halves: 4 A-frags feed 8 B-subtiles.
// ---------------------------------------------------------------------------
__global__ __launch_bounds__(256, 2) void layer_fused_kernel(
        const __hip_bfloat16* __restrict__ h, const __hip_bfloat16* __restrict__ nbr,
        const __hip_bfloat16* __restrict__ wpack_self,
        const __hip_bfloat16* __restrict__ wpack_nbr,
        const float* __restrict__ bias, __hip_bfloat16* __restrict__ out) {
    int wave = threadIdx.x >> 6, lane = threadIdx.x & 63;
    int row0 = blockIdx.x * 128 + wave * 32;
    int lrow = lane & 15, lgrp = lane >> 4;
    const __hip_bfloat16* hr0 = h   + (size_t)(row0 + lrow) * D_FEAT + lgrp * 8;
    const __hip_bfloat16* hr1 = hr0 + (size_t)16 * D_FEAT;
    const __hip_bfloat16* nr0 = nbr + (size_t)(row0 + lrow) * D_FEAT + lgrp * 8;
    const __hip_bfloat16* nr1 = nr0 + (size_t)16 * D_FEAT;

    f32x4 accS[2][4] = {};
    f32x4 accN[2][4] = {};
#pragma unroll
    for (int ks = 0; ks < 4; ks++) {
        bf16x8 ah0 = *(const bf16x8*)(hr0 + ks * 32);
        bf16x8 ah1 = *(const bf16x8*)(hr1 + ks * 32);
        bf16x8 an0 = *(const bf16x8*)(nr0 + ks * 32);
        bf16x8 an1 = *(const bf16x8*)(nr1 + ks * 32);
#pragma unroll
        for (int ns = 0; ns < 4; ns++) {
            bf16x8 bs = *(const bf16x8*)(wpack_self + ((size_t)(ns * 4 + ks) * 64 + lane) * 8);
            accS[0][ns] = __builtin_amdgcn_mfma_f32_16x16x32_bf16(ah0, bs, accS[0][ns], 0, 0, 0);
            accS[1][ns] = __builtin_amdgcn_mfma_f32_16x16x32_bf16(ah1, bs, accS[1][ns], 0, 0, 0);
            bf16x8 bn = *(const bf16x8*)(wpack_nbr + ((size_t)(ns * 4 + ks) * 64 + lane) * 8);
            accN[0][ns] = __builtin_amdgcn_mfma_f32_16x16x32_bf16(an0, bn, accN[0][ns], 0, 0, 0);
            accN[1][ns] = __builtin_amdgcn_mfma_f32_16x16x32_bf16(an1, bn, accN[1][ns], 0, 0, 0);
        }
    }
#pragma unroll
    for (int t = 0; t < 2; t++) {
#pragma unroll
        for (int ns = 0; ns < 4; ns++) {
            int colS = ns * 16 + lrow;
            int colN = HALF + colS;
            float bvS = bias[colS];
            float bvN = bias[colN];
#pragma unroll
            for (int i = 0; i < 4; i++) {
                int r = row0 + t * 16 + lgrp * 4 + i;     // < N_PAD, unguarded
                out[(size_t)r * D_FEAT + colS] =
                    __float2bfloat16(fmaxf(accS[t][ns][i] + bvS, 0.f));
                out[(size_t)r * D_FEAT + colN] =
                    __float2bfloat16(fmaxf(accN[t][ns][i] + bvN, 0.f));
            }
        }
    }
}

// ---------------------------------------------------------------------------
// Fused MLP: out[N,40] = relu(h@W1+b1) @ W2 + b2.
// Phase 1 (mlp1): 32 rows/wave, hidden -> LDS tile [128][HID_STRIDE] bf16
// (same bf16 rounding as the old global round-trip -> bit-identical).
// Phase 2 (mlp2): A-frags from LDS (each wave reads only its own 32 rows).
// ---------------------------------------------------------------------------
__global__ __launch_bounds__(256, 2) void mlp_fused_kernel(
        const __hip_bfloat16* __restrict__ h, const __hip_bfloat16* __restrict__ w1p,
        const float* __restrict__ b1, const __hip_bfloat16* __restrict__ w2p,
        const float* __restrict__ b2, float* __restrict__ out) {
    __shared__ __align__(16) uint16_t hid[128 * HID_STRIDE];   // 67584 B
    int wave = threadIdx.x >> 6, lane = threadIdx.x & 63;
    int row0 = blockIdx.x * 128 + wave * 32;
    int lrow = lane & 15, lgrp = lane >> 4;

    // ---- Phase 1: hidden = relu(h @ W1 + b1) -> LDS ----
    {
        const __hip_bfloat16* ar0 = h + (size_t)(row0 + lrow) * D_FEAT + lgrp * 8;
        const __hip_bfloat16* ar1 = ar0 + (size_t)16 * D_FEAT;
        f32x4 acc[2][16] = {};
#pragma unroll 1
        for (int ks = 0; ks < 4; ks++) {
            bf16x8 a0 = *(const bf16x8*)(ar0 + ks * 32);
            bf16x8 a1 = *(const bf16x8*)(ar1 + ks * 32);
#pragma unroll
            for (int ns = 0; ns < 16; ns++) {
                bf16x8 bfr = *(const bf16x8*)(w1p + ((size_t)(ns * 4 + ks) * 64 + lane) * 8);
                acc[0][ns] = __builtin_amdgcn_mfma_f32_16x16x32_bf16(a0, bfr, acc[0][ns], 0, 0, 0);
                acc[1][ns] = __builtin_amdgcn_mfma_f32_16x16x32_bf16(a1, bfr, acc[1][ns], 0, 0, 0);
            }
        }
        int lbase = wave * 32;
#pragma unroll
        for (int t = 0; t < 2; t++) {
#pragma unroll
            for (int ns = 0; ns < 16; ns++) {
                int col = ns * 16 + lrow;
                float bv = b1[col];
#pragma unroll
                for (int i = 0; i < 4; i++) {
                    int lr = lbase + t * 16 + lgrp * 4 + i;
                    hid[lr * HID_STRIDE + col] =
                        f2bf_bits(fmaxf(acc[t][ns][i] + bv, 0.f));
                }
            }
        }
    }
    __syncthreads();

    // ---- Phase 2: out = hidden @ W2 + b2 ----
    const uint16_t* br0 = &hid[(wave * 32 + lrow) * HID_STRIDE + lgrp * 8];
    const uint16_t* br1 = br0 + 16 * HID_STRIDE;
    f32x4 acc2[2][3] = {};
#pragma unroll
    for (int ks = 0; ks < 8; ks++) {
        bf16x8 a0 = *(const bf16x8*)(br0 + ks * 32);
        bf16x8 a1 = *(const bf16x8*)(br1 + ks * 32);
#pragma unroll
        for (int ns = 0; ns < 3; ns++) {
            bf16x8 bfr = *(const bf16x8*)(w2p + ((size_t)(ns * 8 + ks) * 64 + lane) * 8);
            acc2[0][ns] = __builtin_amdgcn_mfma_f32_16x16x32_bf16(a0, bfr, acc2[0][ns], 0, 0, 0);
            acc2[1][ns] = __builtin_amdgcn_mfma_f32_16x16x32_bf16(a1, bfr, acc2[1][ns], 0, 0, 0);
        }
    }
#pragma unroll
    for (int t = 0; t < 2; t++) {
#pragma unroll
        for (int ns = 0; ns < 3; ns++) {
            int col = ns * 16 + lrow;
            if (col < LABELS) {
                float bv = b2[col];
#pragma unroll
                for (int i = 0; i < 4; i++) {
                    int r = row0 + t * 16 + lgrp * 4 + i;
                    if (r < N_NODES)                       // d_out: exact size
                        out[(size_t)r * LABELS + col] = acc2[t][ns][i] + bv;
                }
            }
        }
    }
}

// ---------------------------------------------------------------------------
extern "C" void kernel_launch(void* const* d_in, const int* in_sizes, int n_in,
                              void* d_out, int out_size, void* d_ws, size_t ws_size,
                              hipStream_t stream) {
    const float* x      = (const float*)d_in[0];
    const int*   ei     = (const int*)d_in[1];
    const float* selfk  = (const float*)d_in[2];
    const float* nbrk   = (const float*)d_in[3];
    const float* biases = (const float*)d_in[4];
    const float* w1     = (const float*)d_in[5];
    const float* b1     = (const float*)d_in[6];
    const float* w2     = (const float*)d_in[7];
    const float* b2     = (const float*)d_in[8];
    float* out = (float*)d_out;

    const int* row = ei;             // targets
    const int* col = ei + N_EDGES;   // sources

    char* ws = (char*)d_ws;
    size_t off = 0;
    auto alloc = [&](size_t bytes) -> char* {
        char* p = ws + off;
        off = (off + bytes + 255) & ~(size_t)255;
        return p;
    };
    int*   deg       = (int*)  alloc((size_t)N_NODES * 4);
    int*   rowstart  = (int*)  alloc((size_t)N_NODES * 4);
    float* inv_deg   = (float*)alloc((size_t)N_NODES * 4);
    int*   bucket_cursor = (int*)alloc(256 * 4);
    int*   csr_col   = (int*)  alloc((size_t)N_EDGES * 4);
    uint32_t* staged = (uint32_t*)alloc((size_t)NBUCK * BCAP * 4);
    __hip_bfloat16* wpack  = (__hip_bfloat16*)alloc(PK_TOTAL * 2);
    __hip_bfloat16* xb     = (__hip_bfloat16*)alloc((size_t)N_PAD * D_FEAT * 2);
    __hip_bfloat16* hA     = (__hip_bfloat16*)alloc((size_t)N_PAD * D_FEAT * 2);
    __hip_bfloat16* hB     = (__hip_bfloat16*)alloc((size_t)N_PAD * D_FEAT * 2);
    __hip_bfloat16* nbrbuf = (__hip_bfloat16*)alloc((size_t)N_PAD * D_FEAT * 2);

    hipMemsetAsync(bucket_cursor, 0, 256 * 4, stream);

    const int scat_blocks = (N_EDGES + EDGES_PER_BLK - 1) / EDGES_PER_BLK;  // 196
    bucket_scatter_kernel<<<scat_blocks, 1024, 0, stream>>>(row, col, bucket_cursor, staged);
    bucket_fill_kernel<<<NBUCK, 1024, 0, stream>>>(staged, bucket_cursor,
                                                   deg, rowstart, inv_deg, csr_col);

    xcast_kernel<<<(N_NODES * D_FEAT / 4 + 255) / 256, 256, 0, stream>>>(x, xb);
    dim3 pgrid(16, 8);
    pack_all_kernel<<<pgrid, 256, 0, stream>>>(selfk, nbrk, w1, w2, wpack);

    const int agg_blocks   = N_NODES / 16;                 // 4 nodes/wave, 4 waves/block
    const int layer_blocks = N_PAD / 128;                  // 128 rows/block, fused halves
    const int mlp_blocks   = N_PAD / 128;

    const __hip_bfloat16* hcur = xb;
    __hip_bfloat16* bufs[3] = {hA, hB, hA};
    for (int L = 0; L < 3; L++) {
        agg4_kernel<<<agg_blocks, 256, 0, stream>>>(hcur, csr_col, rowstart, deg,
                                                    inv_deg, nbrbuf);
        layer_fused_kernel<<<layer_blocks, 256, 0, stream>>>(
            hcur, nbrbuf, wpack + PK_SELF(L), wpack + PK_NBR(L),
            biases + (size_t)L * (2 * HALF), bufs[L]);
        hcur = bufs[L];
    }

    mlp_fused_kernel<<<mlp_blocks, 256, 0, stream>>>(hcur, wpack + PK_W1, b1,
                                                     wpack + PK_W2, b2, out);
}